// Round 1
// baseline (258.687 us; speedup 1.0000x reference)
//
#include <hip/hip_runtime.h>
#include <cstddef>

#define DIM 2048
#define RANK 8
#define NTOK 8192

// ---------------------------------------------------------------------------
// Setup kernel (1 block): compute E (16x16) such that
//   out_row = x_row + sum_k c[k] * P[:,k],  c = E * [au; av],
//   au = x_row . U, av = x_row . V  (each 8 dots)
// Derivation: omega = P Q^T, P=[U|V], Q=[sV|-sU], G = Q^T P,
//   R = I + P H Q^T, H = 0.5 I + (2I-G)^{-1}(I + 0.5 G)
//   x R^T = x + (xQ) H^T P^T;  (xQ) = [s*av | -s*au]
//   => E[k][j]   = -s * H[k][j+8]   (coef of au[j])
//      E[k][8+j] =  s * H[k][j]     (coef of av[j])
// ---------------------------------------------------------------------------
__global__ __launch_bounds__(768) void rora_setup(
    const float* __restrict__ U, const float* __restrict__ V,
    const float* __restrict__ gate, float* __restrict__ Euv) {
  __shared__ float part[192][4];
  __shared__ float prod[3][8][8];  // 0: U^T U, 1: U^T V, 2: V^T V
  __shared__ float aug[16][33];    // [2I-G | I+0.5G], padded
  const int t = threadIdx.x;

  {
    const int e = t >> 2;        // 0..191 entry
    const int slice = t & 3;     // 0..3 d-slice
    const int p = e >> 6;        // product id
    const int i = (e >> 3) & 7;
    const int j = e & 7;
    const float* A = (p == 2) ? V : U;
    const float* B = (p == 0) ? U : V;
    float a0 = 0.f, a1 = 0.f, a2 = 0.f, a3 = 0.f;
    const int d0 = slice * 512;
    for (int d = d0; d < d0 + 512; d += 4) {
      a0 += A[(d + 0) * RANK + i] * B[(d + 0) * RANK + j];
      a1 += A[(d + 1) * RANK + i] * B[(d + 1) * RANK + j];
      a2 += A[(d + 2) * RANK + i] * B[(d + 2) * RANK + j];
      a3 += A[(d + 3) * RANK + i] * B[(d + 3) * RANK + j];
    }
    part[e][slice] = (a0 + a1) + (a2 + a3);
  }
  __syncthreads();
  if (t < 192) {
    ((float*)prod)[t] = part[t][0] + part[t][1] + part[t][2] + part[t][3];
  }
  __syncthreads();
  const float s = 1.f / (1.f + expf(-gate[0]));
  if (t < 256) {
    const int r = t >> 4, c = t & 15;  // G[r][c]
    float g;
    if (r < 8) g = (c < 8) ? s * prod[1][c][r]            // s * (V^T U)[r][c]
                           : s * prod[2][r][c - 8];       // s * (V^T V)
    else       g = (c < 8) ? -s * prod[0][r - 8][c]       // -s * (U^T U)
                           : -s * prod[1][r - 8][c - 8];  // -s * (U^T V)
    aug[r][c]      = ((r == c) ? 2.f : 0.f) - g;
    aug[r][16 + c] = ((r == c) ? 1.f : 0.f) + 0.5f * g;
  }
  __syncthreads();
  // Gauss-Jordan: solve (2I-G) X = (I + 0.5G); 512 threads own aug elements.
  // Diagonally dominant (|G| ~ 0.03), no pivoting needed.
  const int gi = t >> 5, gj = t & 31;
  for (int k = 0; k < 16; ++k) {
    float pk = 1.f, akj = 0.f, aik = 0.f, aij = 0.f;
    if (t < 512) {
      pk = aug[k][k]; akj = aug[k][gj]; aik = aug[gi][k]; aij = aug[gi][gj];
    }
    __syncthreads();
    if (t < 512) {
      const float rowk = akj / pk;
      aug[gi][gj] = (gi == k) ? rowk : fmaf(-aik, rowk, aij);
    }
    __syncthreads();
  }
  if (t < 256) {
    const int k = t >> 4, j = t & 15;  // holds H[k][j]
    const float H = aug[k][16 + j] + ((k == j) ? 0.5f : 0.f);
    if (j < 8) Euv[k * 16 + 8 + j] = s * H;   // av coefficient
    else       Euv[k * 16 + (j - 8)] = -s * H; // au coefficient
  }
}

// ---------------------------------------------------------------------------
// Main kernel: wave-per-4-rows, two streaming passes over x.
// ---------------------------------------------------------------------------
__global__ __launch_bounds__(256) void rora_main(
    const float* __restrict__ x, const float* __restrict__ U,
    const float* __restrict__ V, const float* __restrict__ Euv,
    float* __restrict__ out) {
  __shared__ float Es[256];
  const int t = threadIdx.x;
  Es[t] = Euv[t];
  __syncthreads();
  const int wave = t >> 6, lane = t & 63;
  const int row0 = blockIdx.x * 16 + wave * 4;

  const float4* __restrict__ x4 = (const float4*)x;
  const float4* __restrict__ U4 = (const float4*)U;
  const float4* __restrict__ V4 = (const float4*)V;
  float4* __restrict__ o4 = (float4*)out;

  float au[4][8], av[4][8];
#pragma unroll
  for (int r = 0; r < 4; ++r)
#pragma unroll
    for (int k = 0; k < 8; ++k) { au[r][k] = 0.f; av[r][k] = 0.f; }

  // Phase 1: au = x.U, av = x.V partials over this lane's d-slice
#pragma unroll
  for (int chunk = 0; chunk < 8; ++chunk) {
    const int d0 = chunk * 256 + lane * 4;
    float xs[4][4];
#pragma unroll
    for (int r = 0; r < 4; ++r) {
      const float4 xv = x4[((size_t)(row0 + r) * DIM + d0) >> 2];
      xs[r][0] = xv.x; xs[r][1] = xv.y; xs[r][2] = xv.z; xs[r][3] = xv.w;
    }
#pragma unroll
    for (int i = 0; i < 4; ++i) {
      const int d = d0 + i;
      const float4 ua = U4[d * 2], ub = U4[d * 2 + 1];
      const float4 va = V4[d * 2], vb = V4[d * 2 + 1];
      const float uu[8] = {ua.x, ua.y, ua.z, ua.w, ub.x, ub.y, ub.z, ub.w};
      const float vv[8] = {va.x, va.y, va.z, va.w, vb.x, vb.y, vb.z, vb.w};
#pragma unroll
      for (int r = 0; r < 4; ++r) {
        const float xi = xs[r][i];
#pragma unroll
        for (int k = 0; k < 8; ++k) {
          au[r][k] = fmaf(xi, uu[k], au[r][k]);
          av[r][k] = fmaf(xi, vv[k], av[r][k]);
        }
      }
    }
  }

  // Wave butterfly reduction: all lanes end with full row dots
#pragma unroll
  for (int m = 1; m < 64; m <<= 1) {
#pragma unroll
    for (int r = 0; r < 4; ++r)
#pragma unroll
      for (int k = 0; k < 8; ++k) {
        au[r][k] += __shfl_xor(au[r][k], m, 64);
        av[r][k] += __shfl_xor(av[r][k], m, 64);
      }
  }

  // c = E * [au; av]
  float c[4][16];
#pragma unroll
  for (int k = 0; k < 16; ++k) {
    float e[16];
#pragma unroll
    for (int j = 0; j < 16; ++j) e[j] = Es[k * 16 + j];
#pragma unroll
    for (int r = 0; r < 4; ++r) {
      float acc = 0.f;
#pragma unroll
      for (int j = 0; j < 8; ++j)
        acc = fmaf(e[j], au[r][j], fmaf(e[8 + j], av[r][j], acc));
      c[r][k] = acc;
    }
  }

  // Phase 2: out = x + sum_k c[k] * [U|V][:,k]
#pragma unroll
  for (int chunk = 0; chunk < 8; ++chunk) {
    const int d0 = chunk * 256 + lane * 4;
    float4 xv[4];
#pragma unroll
    for (int r = 0; r < 4; ++r)
      xv[r] = x4[((size_t)(row0 + r) * DIM + d0) >> 2];
    float os[4][4];
#pragma unroll
    for (int i = 0; i < 4; ++i) {
      const int d = d0 + i;
      const float4 ua = U4[d * 2], ub = U4[d * 2 + 1];
      const float4 va = V4[d * 2], vb = V4[d * 2 + 1];
      const float uu[8] = {ua.x, ua.y, ua.z, ua.w, ub.x, ub.y, ub.z, ub.w};
      const float vv[8] = {va.x, va.y, va.z, va.w, vb.x, vb.y, vb.z, vb.w};
#pragma unroll
      for (int r = 0; r < 4; ++r) {
        float acc = 0.f;
#pragma unroll
        for (int k = 0; k < 8; ++k)
          acc = fmaf(c[r][k], uu[k], fmaf(c[r][8 + k], vv[k], acc));
        os[r][i] = acc;
      }
    }
#pragma unroll
    for (int r = 0; r < 4; ++r) {
      float4 o;
      o.x = xv[r].x + os[r][0];
      o.y = xv[r].y + os[r][1];
      o.z = xv[r].z + os[r][2];
      o.w = xv[r].w + os[r][3];
      o4[((size_t)(row0 + r) * DIM + d0) >> 2] = o;
    }
  }
}

extern "C" void kernel_launch(void* const* d_in, const int* in_sizes, int n_in,
                              void* d_out, int out_size, void* d_ws, size_t ws_size,
                              hipStream_t stream) {
  const float* x    = (const float*)d_in[0];
  const float* U    = (const float*)d_in[1];
  const float* V    = (const float*)d_in[2];
  const float* gate = (const float*)d_in[3];
  float* out = (float*)d_out;
  float* Euv = (float*)d_ws;  // 256 floats of scratch

  rora_setup<<<1, 768, 0, stream>>>(U, V, gate, Euv);
  rora_main<<<NTOK / 16, 256, 0, stream>>>(x, U, V, Euv, out);
}

// Round 2
// 165.339 us; speedup vs baseline: 1.5646x; 1.5646x over previous
//
#include <hip/hip_runtime.h>
#include <cstddef>

#define DIM 2048
#define RANK 8
#define NTOK 8192

// ---------------------------------------------------------------------------
// Setup (1 block, 1024 threads): compute E (16x16), then W = P*E (2048x16)
// stored as 4 float4-planes Wp[q][2048] so main-kernel loads are coalesced.
//   omega = P Q^T, P=[U|V], Q=[sV|-sU], G = Q^T P
//   R = I + P H Q^T, H = 0.5 I + (2I-G)^{-1}(I + 0.5 G)
//   x R^T = x + a . W^T  with a = [x.U | x.V],
//   E[k][j]   = -s*H[k][8+j]  (au coef), E[k][8+j] = s*H[k][j] (av coef)
//   W[d][j]   = sum_k P[d][k] * E[k][j]
// ---------------------------------------------------------------------------
__global__ __launch_bounds__(1024) void rora_setup(
    const float* __restrict__ U, const float* __restrict__ V,
    const float* __restrict__ gate, float* __restrict__ Wp) {
  __shared__ float red[3][16][64];
  __shared__ float prod[3][64];   // 0: U^T U, 1: U^T V, 2: V^T V (i*8+j)
  __shared__ float aug[16][33];   // [2I-G | I+0.5G]
  __shared__ float Es[256];
  const int t = threadIdx.x;
  const int w = t >> 6, l = t & 63;
  const int li = l >> 3, lj = l & 7;

  // Gram partials: wave w covers d-slice [w*128, w*128+128), lane = (li,lj)
  for (int q = 0; q < 3; ++q) {
    const float* A = (q == 2) ? V : U;
    const float* B = (q == 0) ? U : V;
    const int d0 = w * 128;
    float acc = 0.f;
#pragma unroll 4
    for (int dd = 0; dd < 128; ++dd) {
      const int d = d0 + dd;
      acc = fmaf(A[d * 8 + li], B[d * 8 + lj], acc);
    }
    red[q][w][l] = acc;
  }
  __syncthreads();
  if (t < 192) {
    const int q = t >> 6, ij = t & 63;
    float s = 0.f;
#pragma unroll
    for (int sl = 0; sl < 16; ++sl) s += red[q][sl][ij];
    prod[q][ij] = s;
  }
  __syncthreads();
  const float sg = 1.f / (1.f + expf(-gate[0]));
  if (t < 256) {
    const int r = t >> 4, c = t & 15;
    float g;
    if (r < 8) g = (c < 8) ? sg * prod[1][c * 8 + r]          // (V^T U)[r][c]
                           : sg * prod[2][r * 8 + (c - 8)];   // (V^T V)
    else       g = (c < 8) ? -sg * prod[0][(r - 8) * 8 + c]   // -(U^T U)
                           : -sg * prod[1][(r - 8) * 8 + (c - 8)];
    aug[r][c]      = ((r == c) ? 2.f : 0.f) - g;
    aug[r][16 + c] = ((r == c) ? 1.f : 0.f) + 0.5f * g;
  }
  __syncthreads();
  // Gauss-Jordan (diagonally dominant, no pivoting)
  const int gi = t >> 5, gj = t & 31;
  for (int k = 0; k < 16; ++k) {
    float pk = 1.f, akj = 0.f, aik = 0.f, aij = 0.f;
    if (t < 512) {
      pk = aug[k][k]; akj = aug[k][gj]; aik = aug[gi][k]; aij = aug[gi][gj];
    }
    __syncthreads();
    if (t < 512) {
      const float rowk = akj / pk;
      aug[gi][gj] = (gi == k) ? rowk : fmaf(-aik, rowk, aij);
    }
    __syncthreads();
  }
  if (t < 256) {
    const int k = t >> 4, j = t & 15;
    const float H = aug[k][16 + j] + ((k == j) ? 0.5f : 0.f);
    if (j < 8) Es[k * 16 + 8 + j]   = sg * H;   // av coefficient column
    else       Es[k * 16 + (j - 8)] = -sg * H;  // au coefficient column
  }
  __syncthreads();
  // W planes: Wp[q*2048 + d] (float4) = W[d][4q..4q+3]
  const float4* U4 = (const float4*)U;
  const float4* V4 = (const float4*)V;
  float4* W4 = (float4*)Wp;
  for (int pass = 0; pass < 2; ++pass) {
    const int d = pass * 1024 + t;
    const float4 ua = U4[2 * d], ub = U4[2 * d + 1];
    const float4 va = V4[2 * d], vb = V4[2 * d + 1];
    const float p[16] = {ua.x, ua.y, ua.z, ua.w, ub.x, ub.y, ub.z, ub.w,
                         va.x, va.y, va.z, va.w, vb.x, vb.y, vb.z, vb.w};
    float wv[16];
#pragma unroll
    for (int j = 0; j < 16; ++j) {
      float acc = 0.f;
#pragma unroll
      for (int k = 0; k < 16; ++k) acc = fmaf(p[k], Es[k * 16 + j], acc);
      wv[j] = acc;
    }
#pragma unroll
    for (int q = 0; q < 4; ++q)
      W4[q * 2048 + d] =
          make_float4(wv[4 * q], wv[4 * q + 1], wv[4 * q + 2], wv[4 * q + 3]);
  }
}

// ---------------------------------------------------------------------------
// Main: 4 waves/block, 2 rows/wave, single HBM pass over x (x staged in LDS).
// Stride-1 lane<->d mapping => all global loads coalesced.
// ---------------------------------------------------------------------------
__global__ __launch_bounds__(256) void rora_main(
    const float* __restrict__ x, const float* __restrict__ U,
    const float* __restrict__ V, const float* __restrict__ Wp,
    float* __restrict__ out) {
  __shared__ float xs[8][2048];  // 64 KB -> 2 blocks/CU
  const int t = threadIdx.x;
  const int wv = t >> 6, lane = t & 63;
  const int row0 = blockIdx.x * 8 + wv * 2;

  const float4* x4 = (const float4*)x;
  const float4* U4 = (const float4*)U;
  const float4* V4 = (const float4*)V;
  const float4* W4 = (const float4*)Wp;

  // stage this wave's 2 rows into LDS (coalesced float4)
  float4* xl0 = (float4*)&xs[wv * 2][0];
  float4* xl1 = (float4*)&xs[wv * 2 + 1][0];
  const size_t rb0 = (size_t)row0 * 512;
  const size_t rb1 = (size_t)(row0 + 1) * 512;
#pragma unroll
  for (int i = 0; i < 8; ++i) {
    const int c = i * 64 + lane;
    xl0[c] = x4[rb0 + c];
    xl1[c] = x4[rb1 + c];
  }

  float a0[16], a1[16];
#pragma unroll
  for (int k = 0; k < 16; ++k) { a0[k] = 0.f; a1[k] = 0.f; }

  const float* xr0 = &xs[wv * 2][0];
  const float* xr1 = &xs[wv * 2 + 1][0];

  // phase 1: a = [x.U | x.V], lane covers d = i*64+lane (stride-1)
#pragma unroll 4
  for (int i = 0; i < 32; ++i) {
    const int d = i * 64 + lane;
    const float4 ua = U4[2 * d], ub = U4[2 * d + 1];
    const float4 va = V4[2 * d], vb = V4[2 * d + 1];
    const float x0 = xr0[d], x1 = xr1[d];
    const float uu[8] = {ua.x, ua.y, ua.z, ua.w, ub.x, ub.y, ub.z, ub.w};
    const float vvv[8] = {va.x, va.y, va.z, va.w, vb.x, vb.y, vb.z, vb.w};
#pragma unroll
    for (int k = 0; k < 8; ++k) {
      a0[k]     = fmaf(x0, uu[k], a0[k]);
      a1[k]     = fmaf(x1, uu[k], a1[k]);
      a0[8 + k] = fmaf(x0, vvv[k], a0[8 + k]);
      a1[8 + k] = fmaf(x1, vvv[k], a1[8 + k]);
    }
  }

  // wave butterfly: all lanes get full row dots
#pragma unroll
  for (int m = 1; m < 64; m <<= 1) {
#pragma unroll
    for (int k = 0; k < 16; ++k) {
      a0[k] += __shfl_xor(a0[k], m, 64);
      a1[k] += __shfl_xor(a1[k], m, 64);
    }
  }

  // phase 2: out[d] = x[d] + sum_j a[j]*W[d][j]  (W planes coalesced)
  float* o0 = out + (size_t)row0 * DIM;
  float* o1 = out + (size_t)(row0 + 1) * DIM;
#pragma unroll 4
  for (int i = 0; i < 32; ++i) {
    const int d = i * 64 + lane;
    const float4 w0 = W4[d], w1 = W4[2048 + d];
    const float4 w2 = W4[4096 + d], w3 = W4[6144 + d];
    const float ww[16] = {w0.x, w0.y, w0.z, w0.w, w1.x, w1.y, w1.z, w1.w,
                          w2.x, w2.y, w2.z, w2.w, w3.x, w3.y, w3.z, w3.w};
    float acc0 = 0.f, acc1 = 0.f;
#pragma unroll
    for (int k = 0; k < 16; ++k) {
      acc0 = fmaf(a0[k], ww[k], acc0);
      acc1 = fmaf(a1[k], ww[k], acc1);
    }
    o0[d] = xr0[d] + acc0;
    o1[d] = xr1[d] + acc1;
  }
}

extern "C" void kernel_launch(void* const* d_in, const int* in_sizes, int n_in,
                              void* d_out, int out_size, void* d_ws, size_t ws_size,
                              hipStream_t stream) {
  const float* x    = (const float*)d_in[0];
  const float* U    = (const float*)d_in[1];
  const float* V    = (const float*)d_in[2];
  const float* gate = (const float*)d_in[3];
  float* out = (float*)d_out;
  float* Wp  = (float*)d_ws;  // 2048*16 floats = 128 KB scratch

  rora_setup<<<1, 1024, 0, stream>>>(U, V, gate, Wp);
  rora_main<<<NTOK / 8, 256, 0, stream>>>(x, U, V, Wp, out);
}

// Round 4
// 143.410 us; speedup vs baseline: 1.8038x; 1.1529x over previous
//
#include <hip/hip_runtime.h>
#include <cstddef>

#define DIM 2048
#define RANK 8
#define NTOK 8192
#define GRAM_BLOCKS 64

// ws layout: exactly [0, 128 KB) — proven safe in round 2.
//   [0, 48 KB): gram partials (transient)
//   [0, 128 KB): W planes (written by rora_solve AFTER partials are consumed;
//                single-block __syncthreads makes the overwrite safe)
// Math (validated rounds 1-3):
//   omega = P Q^T, P=[U|V], Q=[sV|-sU], G = Q^T P
//   R = I + P H Q^T, H = 0.5 I + (2I-G)^{-1}(I + 0.5 G)
//   x R^T = x + a . W^T,  a = [x.U | x.V],  W = P * E
//   E[k][j] = -s*H[k][8+j] (au coef),  E[k][8+j] = s*H[k][j] (av coef)

// ---------------------------------------------------------------------------
// 1) Gram partials: block b covers d in [b*32, b*32+32), thread = (q,i,j)
// ---------------------------------------------------------------------------
__global__ __launch_bounds__(192) void rora_gram(
    const float* __restrict__ U, const float* __restrict__ V,
    float* __restrict__ part) {
  const int t = threadIdx.x;          // 0..191
  const int b = blockIdx.x;           // 0..63
  const int q = t >> 6;               // 0: U^T U, 1: U^T V, 2: V^T V
  const int i = (t >> 3) & 7, j = t & 7;
  const float* A = (q == 2) ? V : U;
  const float* B = (q == 0) ? U : V;
  const int d0 = b * 32;
  float acc = 0.f;
#pragma unroll 8
  for (int dd = 0; dd < 32; ++dd) {
    const int d = d0 + dd;
    acc = fmaf(A[d * 8 + i], B[d * 8 + j], acc);
  }
  part[b * 192 + t] = acc;
}

// ---------------------------------------------------------------------------
// 2) One block: reduce partials -> Gauss-Jordan -> E (LDS only) -> W planes.
//    W overwrites the partial region only after partials are fully consumed.
// ---------------------------------------------------------------------------
__global__ __launch_bounds__(512) void rora_solve(
    const float* __restrict__ part, const float* __restrict__ U,
    const float* __restrict__ V, const float* __restrict__ gate,
    float* __restrict__ Wp) {
  __shared__ float prod[192];       // [q*64 + i*8 + j]
  __shared__ float aug[16][33];
  __shared__ float Es[256];
  const int t = threadIdx.x;
  if (t < 192) {
    float s = 0.f;
    for (int b = 0; b < GRAM_BLOCKS; ++b) s += part[b * 192 + t];
    prod[t] = s;
  }
  __syncthreads();   // all part reads done before any Wp write below
  const float sg = 1.f / (1.f + expf(-gate[0]));
  if (t < 256) {
    const int r = t >> 4, c = t & 15;
    float g;
    if (r < 8) g = (c < 8) ? sg * prod[64 + c * 8 + r]            // (V^T U)
                           : sg * prod[128 + r * 8 + (c - 8)];    // (V^T V)
    else       g = (c < 8) ? -sg * prod[(r - 8) * 8 + c]          // -(U^T U)
                           : -sg * prod[64 + (r - 8) * 8 + (c - 8)];
    aug[r][c]      = ((r == c) ? 2.f : 0.f) - g;
    aug[r][16 + c] = ((r == c) ? 1.f : 0.f) + 0.5f * g;
  }
  __syncthreads();
  // Gauss-Jordan (diagonally dominant, no pivoting); 512 threads own cells
  const int gi = t >> 5, gj = t & 31;
  for (int k = 0; k < 16; ++k) {
    const float pk = aug[k][k], akj = aug[k][gj];
    const float aik = aug[gi][k], aij = aug[gi][gj];
    __syncthreads();
    const float rowk = akj / pk;
    aug[gi][gj] = (gi == k) ? rowk : fmaf(-aik, rowk, aij);
    __syncthreads();
  }
  if (t < 256) {
    const int k = t >> 4, j = t & 15;
    const float H = aug[k][16 + j] + ((k == j) ? 0.5f : 0.f);
    if (j < 8) Es[k * 16 + 8 + j]   = sg * H;   // av coefficient
    else       Es[k * 16 + (j - 8)] = -sg * H;  // au coefficient
  }
  __syncthreads();
  // W planes: W4[q*2048 + d] = W[d][4q..4q+3],  W = P * E
  const float4* U4 = (const float4*)U;
  const float4* V4 = (const float4*)V;
  float4* W4 = (float4*)Wp;
  for (int d0 = 0; d0 < DIM; d0 += 512) {
    const int d = d0 + t;
    const float4 ua = U4[2 * d], ub = U4[2 * d + 1];
    const float4 va = V4[2 * d], vb = V4[2 * d + 1];
    const float p[16] = {ua.x, ua.y, ua.z, ua.w, ub.x, ub.y, ub.z, ub.w,
                         va.x, va.y, va.z, va.w, vb.x, vb.y, vb.z, vb.w};
    float wv[16];
#pragma unroll
    for (int j = 0; j < 16; ++j) {
      float acc = 0.f;
#pragma unroll
      for (int k = 0; k < 16; ++k) acc = fmaf(p[k], Es[k * 16 + j], acc);
      wv[j] = acc;
    }
#pragma unroll
    for (int q = 0; q < 4; ++q)
      W4[q * 2048 + d] =
          make_float4(wv[4 * q], wv[4 * q + 1], wv[4 * q + 2], wv[4 * q + 3]);
  }
}

// ---------------------------------------------------------------------------
// 3) Main: 4 waves/block, 4 rows/wave, two d-sweeps (x re-read; L3-resident).
//    Lane owns d = i*64+lane (stride-1): all global accesses coalesced.
//    4 rows/wave amortizes U/V/W cache traffic 4x (2 GB -> 512 MB).
// ---------------------------------------------------------------------------
__global__ __launch_bounds__(256) void rora_main(
    const float* __restrict__ x, const float* __restrict__ U,
    const float* __restrict__ V, const float* __restrict__ Wp,
    float* __restrict__ out) {
  const int t = threadIdx.x;
  const int wv = t >> 6, lane = t & 63;
  const int row0 = (blockIdx.x * 4 + wv) * 4;
  const float* xr = x + (size_t)row0 * DIM;
  float* orow = out + (size_t)row0 * DIM;
  const float4* U4 = (const float4*)U;
  const float4* V4 = (const float4*)V;
  const float4* W4 = (const float4*)Wp;

  float a[4][16];
#pragma unroll
  for (int r = 0; r < 4; ++r)
#pragma unroll
    for (int k = 0; k < 16; ++k) a[r][k] = 0.f;

  // phase 1: a[r] = [x_r.U | x_r.V] partials over this lane's d-slice
#pragma unroll 2
  for (int i = 0; i < 32; ++i) {
    const int d = i * 64 + lane;
    const float4 ua = U4[2 * d], ub = U4[2 * d + 1];
    const float4 va = V4[2 * d], vb = V4[2 * d + 1];
    const float uu[16] = {ua.x, ua.y, ua.z, ua.w, ub.x, ub.y, ub.z, ub.w,
                          va.x, va.y, va.z, va.w, vb.x, vb.y, vb.z, vb.w};
    float xv[4];
#pragma unroll
    for (int r = 0; r < 4; ++r) xv[r] = xr[(size_t)r * DIM + d];
#pragma unroll
    for (int r = 0; r < 4; ++r) {
      const float xi = xv[r];
#pragma unroll
      for (int k = 0; k < 16; ++k) a[r][k] = fmaf(xi, uu[k], a[r][k]);
    }
  }

  // wave butterfly: all lanes end with the full row dots
#pragma unroll
  for (int m = 1; m < 64; m <<= 1)
#pragma unroll
    for (int r = 0; r < 4; ++r)
#pragma unroll
      for (int k = 0; k < 16; ++k) a[r][k] += __shfl_xor(a[r][k], m, 64);

  // phase 2: out[r][d] = x[r][d] + sum_k a[r][k] * W[d][k]
#pragma unroll 2
  for (int i = 0; i < 32; ++i) {
    const int d = i * 64 + lane;
    const float4 w0 = W4[d], w1 = W4[2048 + d];
    const float4 w2 = W4[4096 + d], w3 = W4[6144 + d];
    const float ww[16] = {w0.x, w0.y, w0.z, w0.w, w1.x, w1.y, w1.z, w1.w,
                          w2.x, w2.y, w2.z, w2.w, w3.x, w3.y, w3.z, w3.w};
#pragma unroll
    for (int r = 0; r < 4; ++r) {
      float acc = xr[(size_t)r * DIM + d];
#pragma unroll
      for (int k = 0; k < 16; ++k) acc = fmaf(a[r][k], ww[k], acc);
      orow[(size_t)r * DIM + d] = acc;
    }
  }
}

extern "C" void kernel_launch(void* const* d_in, const int* in_sizes, int n_in,
                              void* d_out, int out_size, void* d_ws, size_t ws_size,
                              hipStream_t stream) {
  const float* x    = (const float*)d_in[0];
  const float* U    = (const float*)d_in[1];
  const float* V    = (const float*)d_in[2];
  const float* gate = (const float*)d_in[3];
  float* out = (float*)d_out;

  float* ws = (float*)d_ws;   // part at ws[0,48KB) transient; Wp at ws[0,128KB)

  rora_gram<<<GRAM_BLOCKS, 192, 0, stream>>>(U, V, ws);
  rora_solve<<<1, 512, 0, stream>>>(ws, U, V, gate, ws);
  rora_main<<<NTOK / 16, 256, 0, stream>>>(x, U, V, ws, out);
}